// Round 10
// baseline (4971.462 us; speedup 1.0000x reference)
//
#include <hip/hip_runtime.h>
#include <hip/hip_bf16.h>

#define NFEAT 256
#define HID 64
#define NCLASS 40
#define NUM_LAYERS 3

// ---------------------------------------------------------------------------
// lin1: h = relu(x @ w1.T + b1)   x:[N,256] w1:[64,256] -> h:[N,64]
// ---------------------------------------------------------------------------
__global__ __launch_bounds__(256) void k_lin1(
    const float* __restrict__ x, const float* __restrict__ w1,
    const float* __restrict__ b1, float* __restrict__ h, int n_nodes)
{
    __shared__ float xs[8][NFEAT];     // 8 KB
    __shared__ float part[4][8][HID];  // 8 KB
    const int tid  = threadIdx.x;
    const int wave = tid >> 6;
    const int lane = tid & 63;

    float wreg[64];
#pragma unroll
    for (int k = 0; k < 64; k += 4) {
        float4 v = *reinterpret_cast<const float4*>(&w1[lane * NFEAT + wave * 64 + k]);
        wreg[k] = v.x; wreg[k + 1] = v.y; wreg[k + 2] = v.z; wreg[k + 3] = v.w;
    }

    const int nbatch = (n_nodes + 7) >> 3;
    for (int batch = blockIdx.x; batch < nbatch; batch += gridDim.x) {
        const int n0 = batch * 8;
        {
            const float4* xg = reinterpret_cast<const float4*>(x + (size_t)n0 * NFEAT);
            float4* xsv = reinterpret_cast<float4*>(&xs[0][0]);
#pragma unroll
            for (int i = 0; i < 2; ++i) {
                int idx  = tid + i * 256;
                int node = n0 + (idx >> 6);
                xsv[idx] = (node < n_nodes) ? xg[idx] : make_float4(0.f, 0.f, 0.f, 0.f);
            }
        }
        __syncthreads();
        for (int nl = 0; nl < 8; ++nl) {
            const float4* xrow = reinterpret_cast<const float4*>(&xs[nl][wave * 64]);
            float a0 = 0.f, a1 = 0.f, a2 = 0.f, a3 = 0.f;
#pragma unroll
            for (int kq = 0; kq < 16; ++kq) {
                float4 v = xrow[kq];
                a0 = fmaf(v.x, wreg[4 * kq + 0], a0);
                a1 = fmaf(v.y, wreg[4 * kq + 1], a1);
                a2 = fmaf(v.z, wreg[4 * kq + 2], a2);
                a3 = fmaf(v.w, wreg[4 * kq + 3], a3);
            }
            part[wave][nl][lane] = (a0 + a1) + (a2 + a3);
        }
        __syncthreads();
#pragma unroll
        for (int i = 0; i < 2; ++i) {
            int o = tid + i * 256;
            int nl = o >> 6, j = o & 63;
            int node = n0 + nl;
            if (node < n_nodes) {
                float v = part[0][nl][j] + part[1][nl][j] + part[2][nl][j] + part[3][nl][j]
                          + b1[j];
                h[(size_t)node * HID + j] = fmaxf(v, 0.f);
            }
        }
        __syncthreads();
    }
}

// ---------------------------------------------------------------------------
// CSR build: histogram of dst, exclusive scan, fill col_src  (int32 inputs)
// ---------------------------------------------------------------------------
__global__ void k_hist(const int* __restrict__ ei, int* __restrict__ cnt, int E)
{
    int i = blockIdx.x * blockDim.x + threadIdx.x;
    if (i < E) atomicAdd(&cnt[ei[E + i]], 1);
}

#define SCAN_C 2048
__global__ __launch_bounds__(512) void k_scan1(const int* __restrict__ cnt,
                                               int* __restrict__ btot, int n)
{
    __shared__ int sd[512];
    int b = blockIdx.x, t = threadIdx.x;
    int base = b * SCAN_C + t * 4;
    int s = 0;
#pragma unroll
    for (int i = 0; i < 4; ++i) { int idx = base + i; if (idx < n) s += cnt[idx]; }
    sd[t] = s; __syncthreads();
    for (int off = 256; off > 0; off >>= 1) {
        if (t < off) sd[t] += sd[t + off];
        __syncthreads();
    }
    if (t == 0) btot[b] = sd[0];
}

__global__ __launch_bounds__(1024) void k_scan2(int* __restrict__ btot, int nb)
{
    __shared__ int sd[1024];
    int t = threadIdx.x;
    int v = (t < nb) ? btot[t] : 0;
    sd[t] = v; __syncthreads();
    for (int off = 1; off < 1024; off <<= 1) {
        int x = sd[t];
        int add = (t >= off) ? sd[t - off] : 0;
        __syncthreads();
        sd[t] = x + add;
        __syncthreads();
    }
    if (t < nb) btot[t] = sd[t] - v;  // exclusive
}

__global__ __launch_bounds__(512) void k_scan3(const int* __restrict__ cnt,
                                               const int* __restrict__ btot,
                                               int* __restrict__ row_ptr,
                                               int* __restrict__ cursor, int n)
{
    __shared__ int sth[512];
    int b = blockIdx.x, t = threadIdx.x;
    int base = b * SCAN_C + t * 4;
    int v[4]; int s = 0;
#pragma unroll
    for (int i = 0; i < 4; ++i) { int idx = base + i; v[i] = (idx < n) ? cnt[idx] : 0; s += v[i]; }
    sth[t] = s; __syncthreads();
    int mine = s;
    for (int off = 1; off < 512; off <<= 1) {
        int x = sth[t];
        int add = (t >= off) ? sth[t - off] : 0;
        __syncthreads();
        sth[t] = x + add;
        __syncthreads();
    }
    int carry = btot[b] + (sth[t] - mine);
#pragma unroll
    for (int i = 0; i < 4; ++i) {
        int idx = base + i;
        if (idx < n) {
            row_ptr[idx] = carry;
            cursor[idx]  = carry;
            carry += v[i];
            if (idx == n - 1) row_ptr[n] = carry;  // = E
        }
    }
}

__global__ void k_fill(const int* __restrict__ ei, int* __restrict__ cursor,
                       int* __restrict__ col_src, int E)
{
    int i = blockIdx.x * blockDim.x + threadIdx.x;
    if (i < E) {
        int dst = ei[E + i];
        int p = atomicAdd(&cursor[dst], 1);
        col_src[p] = ei[i];
    }
}

// ---------------------------------------------------------------------------
// aggregation: ah[n] = sum_{e: dst=n} h[src[e]]   (wave per node, lane = feat)
// ---------------------------------------------------------------------------
__global__ __launch_bounds__(256) void k_agg(
    const float* __restrict__ h, const int* __restrict__ row_ptr,
    const int* __restrict__ col_src, float* __restrict__ ah, int n_nodes)
{
    int wid    = (blockIdx.x * blockDim.x + threadIdx.x) >> 6;
    int lane   = threadIdx.x & 63;
    int nwaves = (gridDim.x * blockDim.x) >> 6;
    for (int node = wid; node < n_nodes; node += nwaves) {
        int e0 = row_ptr[node], e1 = row_ptr[node + 1];
        float acc = 0.f;
        int e = e0;
        for (; e + 4 <= e1; e += 4) {
            int s0 = col_src[e], s1 = col_src[e + 1], s2 = col_src[e + 2], s3 = col_src[e + 3];
            float v0 = h[(size_t)s0 * HID + lane];
            float v1 = h[(size_t)s1 * HID + lane];
            float v2 = h[(size_t)s2 * HID + lane];
            float v3 = h[(size_t)s3 * HID + lane];
            acc += (v0 + v1) + (v2 + v3);
        }
        for (; e < e1; ++e) acc += h[(size_t)col_src[e] * HID + lane];
        ah[(size_t)node * HID + lane] = acc;
    }
}

// ---------------------------------------------------------------------------
// Wic[l][j][k] = sum_m w_ih[j][m] * gg_w[l][k][m]
// (agg = segsum(h) @ gg_w[l]  =>  gi = segsum(h) @ (gg_w[l] @ w_ih.T))
// ---------------------------------------------------------------------------
__global__ void k_wic(const float* __restrict__ gg_w, const float* __restrict__ w_ih,
                      float* __restrict__ Wic)
{
    int idx = blockIdx.x * blockDim.x + threadIdx.x;
    if (idx < NUM_LAYERS * 192 * 64) {
        int l = idx / (192 * 64);
        int j = (idx / 64) % 192;
        int k = idx % 64;
        const float* gw = gg_w + ((size_t)l * 64 + k) * 64;
        const float* wi = w_ih + (size_t)j * 64;
        float acc = 0.f;
#pragma unroll 4
        for (int m = 0; m < 64; ++m) acc = fmaf(wi[m], gw[m], acc);
        Wic[idx] = acc;
    }
}

// ---------------------------------------------------------------------------
// fused GRU v5: thread = node; ar[64]+hr[64] in VGPRs; weights in LDS (96 KB)
// read wave-uniform (broadcast, conflict-free, vector pipe — avoids r9's
// s_load SGPR-pressure spiral and its low-occupancy latency exposure).
// __launch_bounds__(512, 1): 2nd arg = min BLOCKS/CU (CUDA semantics,
// confirmed r3: (512,2)->cap 128 exact; r9: (256,1)->cap 256). 96 KB LDS
// forces 1 block/CU anyway -> 2 waves/SIMD, VGPR cap 256, ~200 used.
// Persistent 256 blocks (1/CU): weights staged ONCE, grid-stride chunks
// (removes the 1.53-round tail of a 391-block launch).
// hold re-read from global per j (static reg indices everywhere, rule #20).
// VALU floor: 24576 FMA/thread -> 62 us/layer.
// ---------------------------------------------------------------------------
#define GRU5_BLK 512
__global__ __launch_bounds__(GRU5_BLK, 1) void k_gru5(
    const float* __restrict__ ah, float* __restrict__ h,
    const float* __restrict__ Wic, const float* __restrict__ whh,
    const float* __restrict__ b_ih, const float* __restrict__ b_hh, int n_nodes)
{
    __shared__ float wi[192 * 64];  // 48 KB
    __shared__ float wh[192 * 64];  // 48 KB
    const int tid = threadIdx.x;

    {
        const float4* s1 = reinterpret_cast<const float4*>(Wic);
        const float4* s2 = reinterpret_cast<const float4*>(whh);
        float4* d1 = reinterpret_cast<float4*>(wi);
        float4* d2 = reinterpret_cast<float4*>(wh);
        for (int i = tid; i < 3072; i += GRU5_BLK) { d1[i] = s1[i]; d2[i] = s2[i]; }
    }
    __syncthreads();

    const int nchunk = (n_nodes + GRU5_BLK - 1) / GRU5_BLK;
    for (int c = blockIdx.x; c < nchunk; c += gridDim.x) {
        const int node = c * GRU5_BLK + tid;
        const bool act = node < n_nodes;
        const int nc   = act ? node : 0;

        const float4* arow = reinterpret_cast<const float4*>(ah + (size_t)nc * HID);
        const float4* hrow = reinterpret_cast<const float4*>(h + (size_t)nc * HID);

        float ar[64], hr[64];
#pragma unroll
        for (int kq = 0; kq < 16; ++kq) {
            float4 va = arow[kq];
            ar[4 * kq] = va.x; ar[4 * kq + 1] = va.y; ar[4 * kq + 2] = va.z; ar[4 * kq + 3] = va.w;
            float4 vh = hrow[kq];
            hr[4 * kq] = vh.x; hr[4 * kq + 1] = vh.y; hr[4 * kq + 2] = vh.z; hr[4 * kq + 3] = vh.w;
        }

        for (int j = 0; j < 64; ++j) {
            // original h[j] for the z-blend: scalar global re-read (L1-hot;
            // read-before-write in program order), avoids runtime reg index
            float hold = act ? h[(size_t)node * HID + j] : 0.f;

            const float4* wr = reinterpret_cast<const float4*>(&wi[(size_t)j * 64]);
            const float4* wz = reinterpret_cast<const float4*>(&wi[(size_t)(64 + j) * 64]);
            const float4* wn = reinterpret_cast<const float4*>(&wi[(size_t)(128 + j) * 64]);
            const float4* vr = reinterpret_cast<const float4*>(&wh[(size_t)j * 64]);
            const float4* vz = reinterpret_cast<const float4*>(&wh[(size_t)(64 + j) * 64]);
            const float4* vn = reinterpret_cast<const float4*>(&wh[(size_t)(128 + j) * 64]);

            float air = 0.f, aiz = 0.f, ain = 0.f;
            float bhr = 0.f, bhz = 0.f, bhn = 0.f;
#pragma unroll
            for (int kq = 0; kq < 16; ++kq) {
                float4 w0 = wr[kq], w1 = wz[kq], w2 = wn[kq];
                float4 w3 = vr[kq], w4 = vz[kq], w5 = vn[kq];
                float a0 = ar[4 * kq], a1 = ar[4 * kq + 1], a2 = ar[4 * kq + 2], a3 = ar[4 * kq + 3];
                float h0 = hr[4 * kq], h1 = hr[4 * kq + 1], h2 = hr[4 * kq + 2], h3 = hr[4 * kq + 3];
                air = fmaf(a0, w0.x, air); air = fmaf(a1, w0.y, air);
                air = fmaf(a2, w0.z, air); air = fmaf(a3, w0.w, air);
                aiz = fmaf(a0, w1.x, aiz); aiz = fmaf(a1, w1.y, aiz);
                aiz = fmaf(a2, w1.z, aiz); aiz = fmaf(a3, w1.w, aiz);
                ain = fmaf(a0, w2.x, ain); ain = fmaf(a1, w2.y, ain);
                ain = fmaf(a2, w2.z, ain); ain = fmaf(a3, w2.w, ain);
                bhr = fmaf(h0, w3.x, bhr); bhr = fmaf(h1, w3.y, bhr);
                bhr = fmaf(h2, w3.z, bhr); bhr = fmaf(h3, w3.w, bhr);
                bhz = fmaf(h0, w4.x, bhz); bhz = fmaf(h1, w4.y, bhz);
                bhz = fmaf(h2, w4.z, bhz); bhz = fmaf(h3, w4.w, bhz);
                bhn = fmaf(h0, w5.x, bhn); bhn = fmaf(h1, w5.y, bhn);
                bhn = fmaf(h2, w5.z, bhn); bhn = fmaf(h3, w5.w, bhn);
            }

            float ir  = air + b_ih[j];
            float iz  = aiz + b_ih[64 + j];
            float in_ = ain + b_ih[128 + j];
            float hrv = bhr + b_hh[j];
            float hzv = bhz + b_hh[64 + j];
            float hnv = bhn + b_hh[128 + j];
            float r  = 1.f / (1.f + __expf(-(ir + hrv)));
            float z  = 1.f / (1.f + __expf(-(iz + hzv)));
            float x2 = in_ + r * hnv;
            float nn = 1.f - 2.f / (__expf(2.f * x2) + 1.f);  // tanh, inf-safe
            if (act) h[(size_t)node * HID + j] = (1.f - z) * nn + z * hold;
        }
    }
}

// ---------------------------------------------------------------------------
// out = softmax(h @ w2.T + b2)  wave per node; lane<40 = class; w2 in VGPRs
// ---------------------------------------------------------------------------
__global__ __launch_bounds__(256) void k_out(
    const float* __restrict__ h, const float* __restrict__ w2,
    const float* __restrict__ b2, float* __restrict__ out, int n_nodes)
{
    const int tid = threadIdx.x, lane = tid & 63;
    float wreg[64];
    float bias = 0.f;
    if (lane < NCLASS) {
#pragma unroll
        for (int k = 0; k < 64; k += 4) {
            float4 v = *reinterpret_cast<const float4*>(&w2[lane * HID + k]);
            wreg[k] = v.x; wreg[k + 1] = v.y; wreg[k + 2] = v.z; wreg[k + 3] = v.w;
        }
        bias = b2[lane];
    } else {
#pragma unroll
        for (int k = 0; k < 64; ++k) wreg[k] = 0.f;
    }
    int wid    = (blockIdx.x * blockDim.x + tid) >> 6;
    int nwaves = (gridDim.x * blockDim.x) >> 6;
    for (int node = wid; node < n_nodes; node += nwaves) {
        const float4* r4 = reinterpret_cast<const float4*>(h + (size_t)node * HID);
        float a0 = bias, a1 = 0.f, a2 = 0.f, a3 = 0.f;
#pragma unroll
        for (int kq = 0; kq < 16; ++kq) {
            float4 v = r4[kq];
            a0 = fmaf(v.x, wreg[4 * kq + 0], a0);
            a1 = fmaf(v.y, wreg[4 * kq + 1], a1);
            a2 = fmaf(v.z, wreg[4 * kq + 2], a2);
            a3 = fmaf(v.w, wreg[4 * kq + 3], a3);
        }
        float lg = (lane < NCLASS) ? (a0 + a1) + (a2 + a3) : -INFINITY;
        float m = lg;
#pragma unroll
        for (int off = 32; off > 0; off >>= 1) m = fmaxf(m, __shfl_xor(m, off, 64));
        float p = (lane < NCLASS) ? __expf(lg - m) : 0.f;
        float s = p;
#pragma unroll
        for (int off = 32; off > 0; off >>= 1) s += __shfl_xor(s, off, 64);
        if (lane < NCLASS) out[(size_t)node * NCLASS + lane] = p / s;
    }
}

// ---------------------------------------------------------------------------
extern "C" void kernel_launch(void* const* d_in, const int* in_sizes, int n_in,
                              void* d_out, int out_size, void* d_ws, size_t ws_size,
                              hipStream_t stream)
{
    const float* x    = (const float*)d_in[0];
    const int*   ei   = (const int*)d_in[1];    // int32 per harness contract
    const float* w1   = (const float*)d_in[2];
    const float* b1   = (const float*)d_in[3];
    const float* gg_w = (const float*)d_in[4];
    const float* w_ih = (const float*)d_in[5];
    const float* w_hh = (const float*)d_in[6];
    const float* b_ih = (const float*)d_in[7];
    const float* b_hh = (const float*)d_in[8];
    const float* w2   = (const float*)d_in[9];
    const float* b2   = (const float*)d_in[10];
    float*       out  = (float*)d_out;

    const int n = in_sizes[0] / NFEAT;   // 200000
    const int E = in_sizes[1] / 2;       // 1200000

    // workspace carve (~110 MB), 256-B aligned slots
    char* ws0 = (char*)d_ws;
    char* ws  = ws0;
    auto carve = [&](size_t bytes) {
        char* p = ws;
        ws += (bytes + 255) & ~(size_t)255;
        return p;
    };
    float* h       = (float*)carve((size_t)n * HID * 4);
    float* ah      = (float*)carve((size_t)n * HID * 4);
    float* Wic     = (float*)carve((size_t)NUM_LAYERS * 192 * 64 * 4);
    int*   row_ptr = (int*)carve((size_t)(n + 1) * 4);
    int*   col_src = (int*)carve((size_t)E * 4);
    int*   cnt     = (int*)carve((size_t)n * 4);
    int*   cursor  = (int*)carve((size_t)n * 4);
    int*   btot    = (int*)carve(8192);

    const int nb = (n + SCAN_C - 1) / SCAN_C;

    hipMemsetAsync(cnt, 0, (size_t)n * 4, stream);
    k_wic<<<(NUM_LAYERS * 192 * 64 + 255) / 256, 256, 0, stream>>>(gg_w, w_ih, Wic);
    k_lin1<<<2048, 256, 0, stream>>>(x, w1, b1, h, n);
    k_hist<<<(E + 255) / 256, 256, 0, stream>>>(ei, cnt, E);
    k_scan1<<<nb, 512, 0, stream>>>(cnt, btot, n);
    k_scan2<<<1, 1024, 0, stream>>>(btot, nb);
    k_scan3<<<nb, 512, 0, stream>>>(cnt, btot, row_ptr, cursor, n);
    k_fill<<<(E + 255) / 256, 256, 0, stream>>>(ei, cursor, col_src, E);

    for (int l = 0; l < NUM_LAYERS; ++l) {
        k_agg<<<2048, 256, 0, stream>>>(h, row_ptr, col_src, ah, n);
        k_gru5<<<256, GRU5_BLK, 0, stream>>>(ah, h, Wic + (size_t)l * 192 * 64,
                                             w_hh, b_ih, b_hh, n);
    }
    k_out<<<2048, 256, 0, stream>>>(h, w2, b2, out, n);
}

// Round 11
// 1553.324 us; speedup vs baseline: 3.2005x; 3.2005x over previous
//
#include <hip/hip_runtime.h>
#include <hip/hip_bf16.h>

#define NFEAT 256
#define HID 64
#define NCLASS 40
#define NUM_LAYERS 3

// ---------------------------------------------------------------------------
// lin1: h = relu(x @ w1.T + b1)   x:[N,256] w1:[64,256] -> h:[N,64]
// ---------------------------------------------------------------------------
__global__ __launch_bounds__(256) void k_lin1(
    const float* __restrict__ x, const float* __restrict__ w1,
    const float* __restrict__ b1, float* __restrict__ h, int n_nodes)
{
    __shared__ float xs[8][NFEAT];     // 8 KB
    __shared__ float part[4][8][HID];  // 8 KB
    const int tid  = threadIdx.x;
    const int wave = tid >> 6;
    const int lane = tid & 63;

    float wreg[64];
#pragma unroll
    for (int k = 0; k < 64; k += 4) {
        float4 v = *reinterpret_cast<const float4*>(&w1[lane * NFEAT + wave * 64 + k]);
        wreg[k] = v.x; wreg[k + 1] = v.y; wreg[k + 2] = v.z; wreg[k + 3] = v.w;
    }

    const int nbatch = (n_nodes + 7) >> 3;
    for (int batch = blockIdx.x; batch < nbatch; batch += gridDim.x) {
        const int n0 = batch * 8;
        {
            const float4* xg = reinterpret_cast<const float4*>(x + (size_t)n0 * NFEAT);
            float4* xsv = reinterpret_cast<float4*>(&xs[0][0]);
#pragma unroll
            for (int i = 0; i < 2; ++i) {
                int idx  = tid + i * 256;
                int node = n0 + (idx >> 6);
                xsv[idx] = (node < n_nodes) ? xg[idx] : make_float4(0.f, 0.f, 0.f, 0.f);
            }
        }
        __syncthreads();
        for (int nl = 0; nl < 8; ++nl) {
            const float4* xrow = reinterpret_cast<const float4*>(&xs[nl][wave * 64]);
            float a0 = 0.f, a1 = 0.f, a2 = 0.f, a3 = 0.f;
#pragma unroll
            for (int kq = 0; kq < 16; ++kq) {
                float4 v = xrow[kq];
                a0 = fmaf(v.x, wreg[4 * kq + 0], a0);
                a1 = fmaf(v.y, wreg[4 * kq + 1], a1);
                a2 = fmaf(v.z, wreg[4 * kq + 2], a2);
                a3 = fmaf(v.w, wreg[4 * kq + 3], a3);
            }
            part[wave][nl][lane] = (a0 + a1) + (a2 + a3);
        }
        __syncthreads();
#pragma unroll
        for (int i = 0; i < 2; ++i) {
            int o = tid + i * 256;
            int nl = o >> 6, j = o & 63;
            int node = n0 + nl;
            if (node < n_nodes) {
                float v = part[0][nl][j] + part[1][nl][j] + part[2][nl][j] + part[3][nl][j]
                          + b1[j];
                h[(size_t)node * HID + j] = fmaxf(v, 0.f);
            }
        }
        __syncthreads();
    }
}

// ---------------------------------------------------------------------------
// CSR build: histogram of dst, exclusive scan, fill col_src  (int32 inputs)
// ---------------------------------------------------------------------------
__global__ void k_hist(const int* __restrict__ ei, int* __restrict__ cnt, int E)
{
    int i = blockIdx.x * blockDim.x + threadIdx.x;
    if (i < E) atomicAdd(&cnt[ei[E + i]], 1);
}

#define SCAN_C 2048
__global__ __launch_bounds__(512) void k_scan1(const int* __restrict__ cnt,
                                               int* __restrict__ btot, int n)
{
    __shared__ int sd[512];
    int b = blockIdx.x, t = threadIdx.x;
    int base = b * SCAN_C + t * 4;
    int s = 0;
#pragma unroll
    for (int i = 0; i < 4; ++i) { int idx = base + i; if (idx < n) s += cnt[idx]; }
    sd[t] = s; __syncthreads();
    for (int off = 256; off > 0; off >>= 1) {
        if (t < off) sd[t] += sd[t + off];
        __syncthreads();
    }
    if (t == 0) btot[b] = sd[0];
}

__global__ __launch_bounds__(1024) void k_scan2(int* __restrict__ btot, int nb)
{
    __shared__ int sd[1024];
    int t = threadIdx.x;
    int v = (t < nb) ? btot[t] : 0;
    sd[t] = v; __syncthreads();
    for (int off = 1; off < 1024; off <<= 1) {
        int x = sd[t];
        int add = (t >= off) ? sd[t - off] : 0;
        __syncthreads();
        sd[t] = x + add;
        __syncthreads();
    }
    if (t < nb) btot[t] = sd[t] - v;  // exclusive
}

__global__ __launch_bounds__(512) void k_scan3(const int* __restrict__ cnt,
                                               const int* __restrict__ btot,
                                               int* __restrict__ row_ptr,
                                               int* __restrict__ cursor, int n)
{
    __shared__ int sth[512];
    int b = blockIdx.x, t = threadIdx.x;
    int base = b * SCAN_C + t * 4;
    int v[4]; int s = 0;
#pragma unroll
    for (int i = 0; i < 4; ++i) { int idx = base + i; v[i] = (idx < n) ? cnt[idx] : 0; s += v[i]; }
    sth[t] = s; __syncthreads();
    int mine = s;
    for (int off = 1; off < 512; off <<= 1) {
        int x = sth[t];
        int add = (t >= off) ? sth[t - off] : 0;
        __syncthreads();
        sth[t] = x + add;
        __syncthreads();
    }
    int carry = btot[b] + (sth[t] - mine);
#pragma unroll
    for (int i = 0; i < 4; ++i) {
        int idx = base + i;
        if (idx < n) {
            row_ptr[idx] = carry;
            cursor[idx]  = carry;
            carry += v[i];
            if (idx == n - 1) row_ptr[n] = carry;  // = E
        }
    }
}

__global__ void k_fill(const int* __restrict__ ei, int* __restrict__ cursor,
                       int* __restrict__ col_src, int E)
{
    int i = blockIdx.x * blockDim.x + threadIdx.x;
    if (i < E) {
        int dst = ei[E + i];
        int p = atomicAdd(&cursor[dst], 1);
        col_src[p] = ei[i];
    }
}

// ---------------------------------------------------------------------------
// aggregation: ah[n] = sum_{e: dst=n} h[src[e]]   (wave per node, lane = feat)
// ---------------------------------------------------------------------------
__global__ __launch_bounds__(256) void k_agg(
    const float* __restrict__ h, const int* __restrict__ row_ptr,
    const int* __restrict__ col_src, float* __restrict__ ah, int n_nodes)
{
    int wid    = (blockIdx.x * blockDim.x + threadIdx.x) >> 6;
    int lane   = threadIdx.x & 63;
    int nwaves = (gridDim.x * blockDim.x) >> 6;
    for (int node = wid; node < n_nodes; node += nwaves) {
        int e0 = row_ptr[node], e1 = row_ptr[node + 1];
        float acc = 0.f;
        int e = e0;
        for (; e + 4 <= e1; e += 4) {
            int s0 = col_src[e], s1 = col_src[e + 1], s2 = col_src[e + 2], s3 = col_src[e + 3];
            float v0 = h[(size_t)s0 * HID + lane];
            float v1 = h[(size_t)s1 * HID + lane];
            float v2 = h[(size_t)s2 * HID + lane];
            float v3 = h[(size_t)s3 * HID + lane];
            acc += (v0 + v1) + (v2 + v3);
        }
        for (; e < e1; ++e) acc += h[(size_t)col_src[e] * HID + lane];
        ah[(size_t)node * HID + lane] = acc;
    }
}

// ---------------------------------------------------------------------------
// Wic[l][j][k] = sum_m w_ih[j][m] * gg_w[l][k][m]
// (agg = segsum(h) @ gg_w[l]  =>  gi = segsum(h) @ (gg_w[l] @ w_ih.T))
// ---------------------------------------------------------------------------
__global__ void k_wic(const float* __restrict__ gg_w, const float* __restrict__ w_ih,
                      float* __restrict__ Wic)
{
    int idx = blockIdx.x * blockDim.x + threadIdx.x;
    if (idx < NUM_LAYERS * 192 * 64) {
        int l = idx / (192 * 64);
        int j = (idx / 64) % 192;
        int k = idx % 64;
        const float* gw = gg_w + ((size_t)l * 64 + k) * 64;
        const float* wi = w_ih + (size_t)j * 64;
        float acc = 0.f;
#pragma unroll 4
        for (int m = 0; m < 64; ++m) acc = fmaf(wi[m], gw[m], acc);
        Wic[idx] = acc;
    }
}

// ---------------------------------------------------------------------------
// GRU pass 1 (k_gi): gi[j][idx] = ah[node] . Wic[j] + b_ih[j]  for j in [0,192)
//  - thread = node; ar row loaded ONCE into 64 VGPRs (all indices static)
//  - weights via wave-uniform s_load (scalar cache, zero VGPR/LDS)
//  - gi stored TRANSPOSED [192][cN] -> coalesced stores/loads
//  - UNCHANGED from r8 (fits its register budget; not in top-5)
// ---------------------------------------------------------------------------
__global__ __launch_bounds__(256) void k_gi(
    const float* __restrict__ ah, const float* __restrict__ Wic,
    const float* __restrict__ b_ih, float* __restrict__ gi,
    int cbase, int cN, int n_nodes)
{
    const int idx = blockIdx.x * 256 + threadIdx.x;
    if (idx >= cN) return;
    const int node = cbase + idx;
    if (node >= n_nodes) return;

    float ar[64];
    {
        const float4* arow = reinterpret_cast<const float4*>(ah + (size_t)node * HID);
#pragma unroll
        for (int kq = 0; kq < 16; ++kq) {
            float4 v = arow[kq];
            ar[4 * kq] = v.x; ar[4 * kq + 1] = v.y; ar[4 * kq + 2] = v.z; ar[4 * kq + 3] = v.w;
        }
    }

    for (int jt = 0; jt < 192; jt += 8) {
        float acc[8];
#pragma unroll
        for (int q = 0; q < 8; ++q) acc[q] = b_ih[jt + q];

#pragma unroll
        for (int kq = 0; kq < 16; ++kq) {
            float a0 = ar[4 * kq], a1 = ar[4 * kq + 1], a2 = ar[4 * kq + 2], a3 = ar[4 * kq + 3];
#pragma unroll
            for (int q = 0; q < 8; ++q) {
                const float* w = Wic + (size_t)(jt + q) * 64 + 4 * kq;  // uniform -> s_load
                acc[q] = fmaf(a0, w[0], acc[q]);
                acc[q] = fmaf(a1, w[1], acc[q]);
                acc[q] = fmaf(a2, w[2], acc[q]);
                acc[q] = fmaf(a3, w[3], acc[q]);
            }
        }
#pragma unroll
        for (int q = 0; q < 8; ++q) gi[(size_t)(jt + q) * cN + idx] = acc[q];
    }
}

// ---------------------------------------------------------------------------
// GRU pass 2 (k_gfin): gh = h . whh + b_hh ; gates ; in-place h update
//  - thread = node; hr row in 64 VGPRs, all indices compile-time static
//  - __launch_bounds__(256, 1): THE register-budget lever. Session evidence:
//    bare/(waves_per_eu)/(512,1) all leave the allocator's heuristic at a
//    64-128 cap -> hr[64] spills to scratch (r7: VGPR 52, r8: 56, 116-159 MB
//    scratch write-back, 203-214 us). (256,1) verifiably sets cap 256 (r9).
//    Need ~115 VGPR -> no spill, ~4 waves/SIMD runtime occupancy.
//  - gi rows loaded coalesced (12 dwords per tile, issued early)
//  - hold4 re-read from global per tile (rule #20: no runtime reg indexing)
// ---------------------------------------------------------------------------
__global__ __launch_bounds__(256, 1) void k_gfin(
    const float* __restrict__ gi, float* __restrict__ h,
    const float* __restrict__ whh, const float* __restrict__ b_hh,
    int cbase, int cN, int n_nodes)
{
    const int idx = blockIdx.x * 256 + threadIdx.x;
    if (idx >= cN) return;
    const int node = cbase + idx;
    if (node >= n_nodes) return;

    const float4* hrow = reinterpret_cast<const float4*>(h + (size_t)node * HID);
    float4*       wrow = reinterpret_cast<float4*>(h + (size_t)node * HID);

    float hr[64];
#pragma unroll
    for (int kq = 0; kq < 16; ++kq) {
        float4 v = hrow[kq];
        hr[4 * kq] = v.x; hr[4 * kq + 1] = v.y; hr[4 * kq + 2] = v.z; hr[4 * kq + 3] = v.w;
    }

    for (int jt = 0; jt < 64; jt += 4) {
        // original h[jt..jt+3] for the z-blend: fresh global load (L1-hot,
        // not yet overwritten), avoids runtime indexing into hr[]
        float4 hold4 = hrow[jt >> 2];

        // gi gate values for this tile (coalesced dword loads, issued early)
        float gr[4], gz[4], gn[4];
#pragma unroll
        for (int q = 0; q < 4; ++q) {
            gr[q] = gi[(size_t)(jt + q) * cN + idx];
            gz[q] = gi[(size_t)(64 + jt + q) * cN + idx];
            gn[q] = gi[(size_t)(128 + jt + q) * cN + idx];
        }

        float ar_[4], az_[4], an_[4];
#pragma unroll
        for (int q = 0; q < 4; ++q) {
            ar_[q] = b_hh[jt + q];
            az_[q] = b_hh[64 + jt + q];
            an_[q] = b_hh[128 + jt + q];
        }

#pragma unroll
        for (int kq = 0; kq < 16; ++kq) {
            float h0 = hr[4 * kq], h1 = hr[4 * kq + 1], h2 = hr[4 * kq + 2], h3 = hr[4 * kq + 3];
#pragma unroll
            for (int q = 0; q < 4; ++q) {
                const float* vr = whh + (size_t)(jt + q) * 64 + 4 * kq;         // uniform
                const float* vz = whh + (size_t)(64 + jt + q) * 64 + 4 * kq;
                const float* vn = whh + (size_t)(128 + jt + q) * 64 + 4 * kq;
                ar_[q] = fmaf(h0, vr[0], ar_[q]); ar_[q] = fmaf(h1, vr[1], ar_[q]);
                ar_[q] = fmaf(h2, vr[2], ar_[q]); ar_[q] = fmaf(h3, vr[3], ar_[q]);
                az_[q] = fmaf(h0, vz[0], az_[q]); az_[q] = fmaf(h1, vz[1], az_[q]);
                az_[q] = fmaf(h2, vz[2], az_[q]); az_[q] = fmaf(h3, vz[3], az_[q]);
                an_[q] = fmaf(h0, vn[0], an_[q]); an_[q] = fmaf(h1, vn[1], an_[q]);
                an_[q] = fmaf(h2, vn[2], an_[q]); an_[q] = fmaf(h3, vn[3], an_[q]);
            }
        }

        float val[4];
        const float hold[4] = {hold4.x, hold4.y, hold4.z, hold4.w};
#pragma unroll
        for (int q = 0; q < 4; ++q) {
            float r  = 1.f / (1.f + __expf(-(gr[q] + ar_[q])));
            float z  = 1.f / (1.f + __expf(-(gz[q] + az_[q])));
            float x2 = gn[q] + r * an_[q];
            float nn = 1.f - 2.f / (__expf(2.f * x2) + 1.f);  // tanh, inf-safe
            val[q] = (1.f - z) * nn + z * hold[q];
        }
        wrow[jt >> 2] = make_float4(val[0], val[1], val[2], val[3]);
    }
}

// ---------------------------------------------------------------------------
// out = softmax(h @ w2.T + b2)  wave per node; lane<40 = class; w2 in VGPRs
// ---------------------------------------------------------------------------
__global__ __launch_bounds__(256) void k_out(
    const float* __restrict__ h, const float* __restrict__ w2,
    const float* __restrict__ b2, float* __restrict__ out, int n_nodes)
{
    const int tid = threadIdx.x, lane = tid & 63;
    float wreg[64];
    float bias = 0.f;
    if (lane < NCLASS) {
#pragma unroll
        for (int k = 0; k < 64; k += 4) {
            float4 v = *reinterpret_cast<const float4*>(&w2[lane * HID + k]);
            wreg[k] = v.x; wreg[k + 1] = v.y; wreg[k + 2] = v.z; wreg[k + 3] = v.w;
        }
        bias = b2[lane];
    } else {
#pragma unroll
        for (int k = 0; k < 64; ++k) wreg[k] = 0.f;
    }
    int wid    = (blockIdx.x * blockDim.x + tid) >> 6;
    int nwaves = (gridDim.x * blockDim.x) >> 6;
    for (int node = wid; node < n_nodes; node += nwaves) {
        const float4* r4 = reinterpret_cast<const float4*>(h + (size_t)node * HID);
        float a0 = bias, a1 = 0.f, a2 = 0.f, a3 = 0.f;
#pragma unroll
        for (int kq = 0; kq < 16; ++kq) {
            float4 v = r4[kq];
            a0 = fmaf(v.x, wreg[4 * kq + 0], a0);
            a1 = fmaf(v.y, wreg[4 * kq + 1], a1);
            a2 = fmaf(v.z, wreg[4 * kq + 2], a2);
            a3 = fmaf(v.w, wreg[4 * kq + 3], a3);
        }
        float lg = (lane < NCLASS) ? (a0 + a1) + (a2 + a3) : -INFINITY;
        float m = lg;
#pragma unroll
        for (int off = 32; off > 0; off >>= 1) m = fmaxf(m, __shfl_xor(m, off, 64));
        float p = (lane < NCLASS) ? __expf(lg - m) : 0.f;
        float s = p;
#pragma unroll
        for (int off = 32; off > 0; off >>= 1) s += __shfl_xor(s, off, 64);
        if (lane < NCLASS) out[(size_t)node * NCLASS + lane] = p / s;
    }
}

// ---------------------------------------------------------------------------
extern "C" void kernel_launch(void* const* d_in, const int* in_sizes, int n_in,
                              void* d_out, int out_size, void* d_ws, size_t ws_size,
                              hipStream_t stream)
{
    const float* x    = (const float*)d_in[0];
    const int*   ei   = (const int*)d_in[1];    // int32 per harness contract
    const float* w1   = (const float*)d_in[2];
    const float* b1   = (const float*)d_in[3];
    const float* gg_w = (const float*)d_in[4];
    const float* w_ih = (const float*)d_in[5];
    const float* w_hh = (const float*)d_in[6];
    const float* b_ih = (const float*)d_in[7];
    const float* b_hh = (const float*)d_in[8];
    const float* w2   = (const float*)d_in[9];
    const float* b2   = (const float*)d_in[10];
    float*       out  = (float*)d_out;

    const int n = in_sizes[0] / NFEAT;   // 200000
    const int E = in_sizes[1] / 2;       // 1200000

    // workspace carve (base ~110 MB), 256-B aligned slots
    char* ws0 = (char*)d_ws;
    char* ws  = ws0;
    auto carve = [&](size_t bytes) {
        char* p = ws;
        ws += (bytes + 255) & ~(size_t)255;
        return p;
    };
    float* h       = (float*)carve((size_t)n * HID * 4);
    float* ah      = (float*)carve((size_t)n * HID * 4);
    float* Wic     = (float*)carve((size_t)NUM_LAYERS * 192 * 64 * 4);
    int*   row_ptr = (int*)carve((size_t)(n + 1) * 4);
    int*   col_src = (int*)carve((size_t)E * 4);
    int*   cnt     = (int*)carve((size_t)n * 4);
    int*   cursor  = (int*)carve((size_t)n * 4);
    int*   btot    = (int*)carve(8192);

    // gi buffer: [192][chunkN] fp32, as big a chunk as ws allows (prefer full n)
    size_t avail = (ws_size > (size_t)(ws - ws0)) ? ws_size - (size_t)(ws - ws0) : 0;
    int chunkN = (int)(avail / (192 * 4));
    if (chunkN > n) chunkN = n;
    if (chunkN < 8192) chunkN = 8192;  // assume ws is at least ~116 MB total
    float* gi = (float*)ws;

    const int nb = (n + SCAN_C - 1) / SCAN_C;

    hipMemsetAsync(cnt, 0, (size_t)n * 4, stream);
    k_wic<<<(NUM_LAYERS * 192 * 64 + 255) / 256, 256, 0, stream>>>(gg_w, w_ih, Wic);
    k_lin1<<<2048, 256, 0, stream>>>(x, w1, b1, h, n);
    k_hist<<<(E + 255) / 256, 256, 0, stream>>>(ei, cnt, E);
    k_scan1<<<nb, 512, 0, stream>>>(cnt, btot, n);
    k_scan2<<<1, 1024, 0, stream>>>(btot, nb);
    k_scan3<<<nb, 512, 0, stream>>>(cnt, btot, row_ptr, cursor, n);
    k_fill<<<(E + 255) / 256, 256, 0, stream>>>(ei, cursor, col_src, E);

    for (int l = 0; l < NUM_LAYERS; ++l) {
        k_agg<<<2048, 256, 0, stream>>>(h, row_ptr, col_src, ah, n);
        const float* Wl = Wic + (size_t)l * 192 * 64;
        for (int cbase = 0; cbase < n; cbase += chunkN) {
            int cN = (n - cbase < chunkN) ? (n - cbase) : chunkN;
            int grid = (cN + 255) / 256;
            k_gi  <<<grid, 256, 0, stream>>>(ah, Wl, b_ih, gi, cbase, cN, n);
            k_gfin<<<grid, 256, 0, stream>>>(gi, h, w_hh, b_hh, cbase, cN, n);
        }
    }
    k_out<<<2048, 256, 0, stream>>>(h, w2, b2, out, n);
}